// Round 15
// baseline (2850.838 us; speedup 1.0000x reference)
//
#include <hip/hip_runtime.h>
#include <math.h>

#define SS 2048
#define EE 1024
#define EPSD 1e-8
#define EPSF 1e-8f
#define NTH 512          // 8 waves, 2 per SIMD (latency hiding)
#define NW  8
#define NG  32           // cosine groups
#define GS  64           // group size

#define DPP_XOR1 0xB1    // quad_perm [1,0,3,2]
#define DPP_XOR2 0x4E    // quad_perm [2,3,0,1]
#define DPP_HMIR 0x141   // row_half_mirror
#define DPP_MIR  0x140   // row_mirror

using f4 = float __attribute__((ext_vector_type(4)));
using f2 = float __attribute__((ext_vector_type(2)));

// ---- f32 DPP primitives (single mov_dpp per stage) ----
template <int CTRL>
__device__ __forceinline__ float mov_dpp_f32(float v) {
  union { float f; int i; } a; a.f = v;
  const int n = __builtin_amdgcn_mov_dpp(a.i, CTRL, 0xF, 0xF, true);
  union { int i; float f; } r; r.i = n;
  return r.f;
}

template <int CTRL>
__device__ __forceinline__ float dpp_addf(float v) { return v + mov_dpp_f32<CTRL>(v); }

template <int CTRL>
__device__ __forceinline__ void amax_dppf(float& v, int& ix) {
  const float ov = mov_dpp_f32<CTRL>(v);
  const int oi = __builtin_amdgcn_mov_dpp(ix, CTRL, 0xF, 0xF, true);
  if (ov > v || (ov == v && oi < ix)) { v = ov; ix = oi; }
}

__device__ __forceinline__ void foldmaxf(float& v, int& ix, float ov, int oi) {
  if (ov > v || (ov == v && oi < ix)) { v = ov; ix = oi; }
}

// f32 1/sqrt: v_rsq_f32 + 1 Newton (~1 ulp).
__device__ __forceinline__ float rsqrt1f(float x) {
  float y = __builtin_amdgcn_rsqf(x);
  y = y * fmaf(-0.5f * x * y, y, 1.5f);
  return y;
}

// f32 1/x: v_rcp_f32 + 1 Newton (~1 ulp).
__device__ __forceinline__ float rcp1f(float x) {
  float y = __builtin_amdgcn_rcpf(x);
  y = y * fmaf(-x, y, 2.0f);
  return y;
}

// f32 tanh for |z| <= ~1.2, rel err ~2e-7: odd Taylor at z/2 (7 terms) + doubling.
__device__ __forceinline__ float tanh_f32(float z) {
  const float u = 0.5f * z;
  const float s = u * u;
  float P = fmaf(s, -929569.0f / 638512875.0f, 21844.0f / 6081075.0f);  // c15,c13
  P = fmaf(s, P, -1382.0f / 155925.0f);   // c11
  P = fmaf(s, P, 62.0f / 2835.0f);        // c9
  P = fmaf(s, P, -17.0f / 315.0f);        // c7
  P = fmaf(s, P, 2.0f / 15.0f);           // c5
  P = fmaf(s, P, -1.0f / 3.0f);           // c3
  const float t = fmaf(u * s, P, u);      // tanh(z/2)
  const float den = fmaf(t, t, 1.0f);
  return (2.0f * t) * rcp1f(den);
}

__device__ __forceinline__ double wave_sum64(double v) {
#pragma unroll
  for (int off = 32; off > 0; off >>= 1) v += __shfl_down(v, off, 64);
  return v;
}

__global__ void banyan_init(const int* __restrict__ seqs, const float* __restrict__ emb,
                            float* __restrict__ x, double* __restrict__ norms) {
  __shared__ double sh[4];
  const int s = blockIdx.x;
  const int row = seqs[s];
  double acc = 0.0;
  for (int e = threadIdx.x; e < EE; e += 256) {
    const float v = emb[(size_t)row * EE + e];
    x[(size_t)s * EE + e] = v;
    acc += (double)v * (double)v;
  }
  acc = wave_sum64(acc);
  const int lane = threadIdx.x & 63;
  const int w = threadIdx.x >> 6;
  if (lane == 0) sh[w] = acc;
  __syncthreads();
  if (threadIdx.x == 0) norms[s] = sqrt(sh[0] + sh[1] + sh[2] + sh[3]);
}

__global__ void banyan_dots(const float* __restrict__ x, double* __restrict__ num) {
  __shared__ double sh[4];
  const int s = blockIdx.x;
  double acc = 0.0;
  for (int e = threadIdx.x; e < EE; e += 256) {
    acc += (double)x[(size_t)s * EE + e] * (double)x[(size_t)(s + 1) * EE + e];
  }
  acc = wave_sum64(acc);
  const int lane = threadIdx.x & 63;
  const int w = threadIdx.x >> 6;
  if (lane == 0) sh[w] = acc;
  __syncthreads();
  if (threadIdx.x == 0) num[s] = sh[0] + sh[1] + sh[2] + sh[3];
}

// R14 structure at 8 waves (2/SIMD): halved per-thread elementwise work,
// co-resident waves hide LDS/global latency within each phase.
__global__ __launch_bounds__(NTH, 1) void banyan_main(
    float* __restrict__ x, const double* __restrict__ norms_in, const double* __restrict__ num_in,
    const float* __restrict__ Wl, const float* __restrict__ Wr, const float* __restrict__ Bb,
    float* __restrict__ out) {
  __shared__ float cosL[SS];
  __shared__ float rcpN[SS];       // 1 / max(norm, eps)
  __shared__ unsigned listL[SS];   // next lo16, prev hi16 (0xFFFF = -1)
  __shared__ int next2L[SS];       // next[next[s]] (-1 = none)
  __shared__ float gVal[NG];
  __shared__ int gIdx[NG];
  __shared__ float r3v[3][32];     // [sum][row-slot: w*4 + row]

  const int t = threadIdx.x;
  const int lane = t & 63;
  const int w = t >> 6;
  const int m16 = lane & 15;
  const float NEGINF = -__builtin_inff();

  for (int s = t; s < SS; s += NTH) {
    rcpN[s] = (float)(1.0 / fmax(norms_in[s], EPSD));
    const int nx = (s + 1 < SS) ? (s + 1) : -1;
    const int pv = s - 1;
    listL[s] = ((unsigned)nx & 0xFFFFu) | (((unsigned)pv & 0xFFFFu) << 16);
    next2L[s] = (s + 2 < SS) ? (s + 2) : -1;
  }
  __syncthreads();
  for (int s = t; s < SS; s += NTH) {
    cosL[s] = (s < SS - 1)
                  ? (float)((num_in[s] * (double)rcpN[s]) * (double)rcpN[s + 1])
                  : NEGINF;
  }
  __syncthreads();
  for (int m = 0; m < NG / NW; ++m) {
    const int g = w * (NG / NW) + m;
    float v = cosL[g * GS + lane];
    int ix = g * GS + lane;
#pragma unroll
    for (int off = 32; off > 0; off >>= 1) {
      const float ov = __shfl_down(v, off, 64);
      const int oi = __shfl_down(ix, off, 64);
      if (ov > v || (ov == v && oi < ix)) { v = ov; ix = oi; }
    }
    if (lane == 0) { gVal[g] = v; gIdx[g] = ix; }
  }
  __syncthreads();

  // Thread t owns elements {2t, 2t+1} (one 8B chunk).
  const int e0 = 2 * t;
  const f2 wl = *(const f2*)&Wl[e0];
  const f2 wr = *(const f2*)&Wr[e0];
  const f2 bv = *(const f2*)&Bb[e0];
  int head = 0;

  for (int step = 0; step < SS - 1; ++step) {
    // ---- phase 1: argmax over 32 group maxima, crossing-free ----
    float v = gVal[m16];
    int ix = gIdx[m16];
    foldmaxf(v, ix, gVal[m16 + 16], gIdx[m16 + 16]);
    amax_dppf<DPP_XOR1>(v, ix);
    amax_dppf<DPP_XOR2>(v, ix);
    amax_dppf<DPP_HMIR>(v, ix);
    amax_dppf<DPP_MIR>(v, ix);
    const int i = __builtin_amdgcn_readfirstlane(ix);
    // issue i-row load immediately (don't wait for the list round-trip)
    const f2 xi = *(const f2*)&x[(size_t)i * EE + e0];
    const unsigned pki = listL[i];   // broadcast LDS reads
    const int nj_raw = next2L[i];
    const int j = __builtin_amdgcn_readfirstlane((int)(short)(pki & 0xFFFFu));
    const int p = __builtin_amdgcn_readfirstlane((int)(short)(pki >> 16));
    const int nj = __builtin_amdgcn_readfirstlane(nj_raw);
    if (p < 0) head = j;
    const int p2 = (p >= 0) ? p : i;
    const int n2 = (nj >= 0) ? nj : i;

    // ---- phase 2: remaining row loads (one window), tanh, row-partial sums ----
    const f2 xj = *(const f2*)&x[(size_t)j * EE + e0];
    const f2 xp = *(const f2*)&x[(size_t)p2 * EE + e0];
    const f2 xn = *(const f2*)&x[(size_t)n2 * EE + e0];
    const float rcpP = rcpN[p2];
    const float rcpNN = rcpN[n2];
    const int gi_ = i >> 6;
    const int gp_ = (p >= 0) ? (p >> 6) : gi_;
    const int gj_ = j >> 6;
    const int grp = (w == 0) ? gi_ : (w == 1) ? gp_ : gj_;
    const int base = grp * GS + m16;
    // repair-group preloads (only used by w<3; loaded by all for uniformity)
    const float c0 = cosL[base];
    const float c1 = cosL[base + 16];
    const float c2 = cosL[base + 32];
    const float c3 = cosL[base + 48];

    const float q0 = tanh_f32(fmaf(xi.x, wl.x, fmaf(xj.x, wr.x, bv.x)));
    const float q1 = tanh_f32(fmaf(xi.y, wl.y, fmaf(xj.y, wr.y, bv.y)));
    f2 st; st.x = q0; st.y = q1;
    *(f2*)&x[(size_t)j * EE + e0] = st;

    float s0 = fmaf(q0, q0, q1 * q1);
    float s1 = fmaf(xp.x, q0, xp.y * q1);
    float s2 = fmaf(q0, xn.x, q1 * xn.y);
    s1 = (p >= 0) ? s1 : 0.0f;
    s2 = (nj >= 0) ? s2 : 0.0f;
    // DPP-only row reduce (16-lane rows); write 32 row partials
    s0 = dpp_addf<DPP_XOR1>(s0); s1 = dpp_addf<DPP_XOR1>(s1); s2 = dpp_addf<DPP_XOR1>(s2);
    s0 = dpp_addf<DPP_XOR2>(s0); s1 = dpp_addf<DPP_XOR2>(s1); s2 = dpp_addf<DPP_XOR2>(s2);
    s0 = dpp_addf<DPP_HMIR>(s0); s1 = dpp_addf<DPP_HMIR>(s1); s2 = dpp_addf<DPP_HMIR>(s2);
    s0 = dpp_addf<DPP_MIR>(s0);  s1 = dpp_addf<DPP_MIR>(s1);  s2 = dpp_addf<DPP_MIR>(s2);
    if (m16 == 0) {                  // lanes 0,16,32,48: row partials
      const int slot = w * 4 + (lane >> 4);
      r3v[0][slot] = s0; r3v[1][slot] = s1; r3v[2][slot] = s2;
    }
    __syncthreads();  // B

    // ---- phase 3: fold 32 partials + cosines + crossing-free repair ----
    float t0 = r3v[0][m16] + r3v[0][m16 + 16];
    float t1 = r3v[1][m16] + r3v[1][m16 + 16];
    float t2 = r3v[2][m16] + r3v[2][m16 + 16];
    t0 = dpp_addf<DPP_XOR1>(t0); t1 = dpp_addf<DPP_XOR1>(t1); t2 = dpp_addf<DPP_XOR1>(t2);
    t0 = dpp_addf<DPP_XOR2>(t0); t1 = dpp_addf<DPP_XOR2>(t1); t2 = dpp_addf<DPP_XOR2>(t2);
    t0 = dpp_addf<DPP_HMIR>(t0); t1 = dpp_addf<DPP_HMIR>(t1); t2 = dpp_addf<DPP_HMIR>(t2);
    t0 = dpp_addf<DPP_MIR>(t0);  t1 = dpp_addf<DPP_MIR>(t1);  t2 = dpp_addf<DPP_MIR>(t2);
    const float invnn = (t0 > EPSF * EPSF) ? rsqrt1f(t0) : 1e8f;
    const float cosP = (p >= 0) ? (t1 * rcpP) * invnn : NEGINF;
    const float cosJnew = (nj >= 0) ? (t2 * rcpNN) * invnn : NEGINF;
    if (w < 3) {
      // substitute the 3 changed slots, fold 4-in-register, DPP row-reduce
      float cc0 = c0, cc1 = c1, cc2 = c2, cc3 = c3;
      const int pos0 = base, pos1 = base + 16, pos2 = base + 32, pos3 = base + 48;
      if (pos0 == i) cc0 = NEGINF;
      if (p >= 0 && pos0 == p) cc0 = cosP;
      if (pos0 == j) cc0 = cosJnew;
      if (pos1 == i) cc1 = NEGINF;
      if (p >= 0 && pos1 == p) cc1 = cosP;
      if (pos1 == j) cc1 = cosJnew;
      if (pos2 == i) cc2 = NEGINF;
      if (p >= 0 && pos2 == p) cc2 = cosP;
      if (pos2 == j) cc2 = cosJnew;
      if (pos3 == i) cc3 = NEGINF;
      if (p >= 0 && pos3 == p) cc3 = cosP;
      if (pos3 == j) cc3 = cosJnew;
      float cv = cc0; int gx = pos0;
      foldmaxf(cv, gx, cc1, pos1);
      foldmaxf(cv, gx, cc2, pos2);
      foldmaxf(cv, gx, cc3, pos3);
      amax_dppf<DPP_XOR1>(cv, gx);
      amax_dppf<DPP_XOR2>(cv, gx);
      amax_dppf<DPP_HMIR>(cv, gx);
      amax_dppf<DPP_MIR>(cv, gx);
      if (lane == 0) { gVal[grp] = cv; gIdx[grp] = gx; }  // dup groups: same value
    } else if (w == 3 && lane == 0) {  // wave 3: scalar LDS state updates
      cosL[i] = NEGINF;
      cosL[j] = cosJnew;
      rcpN[j] = invnn;
      listL[j] = ((unsigned)nj & 0xFFFFu) | (((unsigned)p & 0xFFFFu) << 16);
      if (p >= 0) {
        cosL[p] = cosP;
        const unsigned lp = listL[p];
        listL[p] = (lp & 0xFFFF0000u) | ((unsigned)j & 0xFFFFu);
        next2L[p] = nj;
        const int pp = (int)(short)(lp >> 16);
        if (pp >= 0) next2L[pp] = j;
      }
    }
    __syncthreads();  // C
  }

  {
    const f2 h = *(const f2*)&x[(size_t)head * EE + e0];
    *(f2*)&out[e0] = h;
  }
}

extern "C" void kernel_launch(void* const* d_in, const int* in_sizes, int n_in,
                              void* d_out, int out_size, void* d_ws, size_t ws_size,
                              hipStream_t stream) {
  const int* seqs = (const int*)d_in[0];
  const float* emb = (const float*)d_in[1];
  const float* Wl = (const float*)d_in[2];
  const float* Wr = (const float*)d_in[3];
  const float* Bb = (const float*)d_in[4];
  float* out = (float*)d_out;

  const size_t xbytesF = (size_t)SS * EE * sizeof(float);
  float* x = (float*)d_ws;
  double* norms = (double*)((char*)d_ws + xbytesF);
  double* num = norms + SS;
  hipLaunchKernelGGL(banyan_init, dim3(SS), dim3(256), 0, stream, seqs, emb, x, norms);
  hipLaunchKernelGGL(banyan_dots, dim3(SS - 1), dim3(256), 0, stream, x, num);
  hipLaunchKernelGGL(banyan_main, dim3(1), dim3(NTH), 0, stream,
                     x, norms, num, Wl, Wr, Bb, out);
}

// Round 16
// 2580.919 us; speedup vs baseline: 1.1046x; 1.1046x over previous
//
#include <hip/hip_runtime.h>
#include <math.h>

#define SS 2048
#define EE 1024
#define EPSD 1e-8
#define EPSF 1e-8f
#define NTH 256          // 4 waves, 1 per SIMD (R15 showed 8 waves regress)
#define NW  4
#define NG  32           // cosine groups
#define GS  64           // group size

#define DPP_XOR1 0xB1    // quad_perm [1,0,3,2]
#define DPP_XOR2 0x4E    // quad_perm [2,3,0,1]
#define DPP_HMIR 0x141   // row_half_mirror
#define DPP_MIR  0x140   // row_mirror

using f4 = float __attribute__((ext_vector_type(4)));
using f2 = float __attribute__((ext_vector_type(2)));

// ---- f32 DPP primitives (single mov_dpp per stage) ----
template <int CTRL>
__device__ __forceinline__ float mov_dpp_f32(float v) {
  union { float f; int i; } a; a.f = v;
  const int n = __builtin_amdgcn_mov_dpp(a.i, CTRL, 0xF, 0xF, true);
  union { int i; float f; } r; r.i = n;
  return r.f;
}

template <int CTRL>
__device__ __forceinline__ float dpp_addf(float v) { return v + mov_dpp_f32<CTRL>(v); }

template <int CTRL>
__device__ __forceinline__ void amax_dppf(float& v, int& ix) {
  const float ov = mov_dpp_f32<CTRL>(v);
  const int oi = __builtin_amdgcn_mov_dpp(ix, CTRL, 0xF, 0xF, true);
  if (ov > v || (ov == v && oi < ix)) { v = ov; ix = oi; }
}

__device__ __forceinline__ void foldmaxf(float& v, int& ix, float ov, int oi) {
  if (ov > v || (ov == v && oi < ix)) { v = ov; ix = oi; }
}

// f32 1/sqrt: v_rsq_f32 + 1 Newton (~1 ulp).
__device__ __forceinline__ float rsqrt1f(float x) {
  float y = __builtin_amdgcn_rsqf(x);
  y = y * fmaf(-0.5f * x * y, y, 1.5f);
  return y;
}

// f32 1/x: v_rcp_f32 + 1 Newton (~1 ulp).
__device__ __forceinline__ float rcp1f(float x) {
  float y = __builtin_amdgcn_rcpf(x);
  y = y * fmaf(-x, y, 2.0f);
  return y;
}

// f32 tanh for |z| <= ~1.2, rel err ~2e-7: odd Taylor at z/2 (7 terms) + doubling.
__device__ __forceinline__ float tanh_f32(float z) {
  const float u = 0.5f * z;
  const float s = u * u;
  float P = fmaf(s, -929569.0f / 638512875.0f, 21844.0f / 6081075.0f);  // c15,c13
  P = fmaf(s, P, -1382.0f / 155925.0f);   // c11
  P = fmaf(s, P, 62.0f / 2835.0f);        // c9
  P = fmaf(s, P, -17.0f / 315.0f);        // c7
  P = fmaf(s, P, 2.0f / 15.0f);           // c5
  P = fmaf(s, P, -1.0f / 3.0f);           // c3
  const float t = fmaf(u * s, P, u);      // tanh(z/2)
  const float den = fmaf(t, t, 1.0f);
  return (2.0f * t) * rcp1f(den);
}

__device__ __forceinline__ double wave_sum64(double v) {
#pragma unroll
  for (int off = 32; off > 0; off >>= 1) v += __shfl_down(v, off, 64);
  return v;
}

__global__ void banyan_init(const int* __restrict__ seqs, const float* __restrict__ emb,
                            float* __restrict__ x, double* __restrict__ norms) {
  __shared__ double sh[4];
  const int s = blockIdx.x;
  const int row = seqs[s];
  double acc = 0.0;
  for (int e = threadIdx.x; e < EE; e += 256) {
    const float v = emb[(size_t)row * EE + e];
    x[(size_t)s * EE + e] = v;
    acc += (double)v * (double)v;
  }
  acc = wave_sum64(acc);
  const int lane = threadIdx.x & 63;
  const int w = threadIdx.x >> 6;
  if (lane == 0) sh[w] = acc;
  __syncthreads();
  if (threadIdx.x == 0) norms[s] = sqrt(sh[0] + sh[1] + sh[2] + sh[3]);
}

__global__ void banyan_dots(const float* __restrict__ x, double* __restrict__ num) {
  __shared__ double sh[4];
  const int s = blockIdx.x;
  double acc = 0.0;
  for (int e = threadIdx.x; e < EE; e += 256) {
    acc += (double)x[(size_t)s * EE + e] * (double)x[(size_t)(s + 1) * EE + e];
  }
  acc = wave_sum64(acc);
  const int lane = threadIdx.x & 63;
  const int w = threadIdx.x >> 6;
  if (lane == 0) sh[w] = acc;
  __syncthreads();
  if (threadIdx.x == 0) num[s] = sh[0] + sh[1] + sh[2] + sh[3];
}

// R14 skeleton (best: 2681us) + stable-group scan moved into the global-load
// window (phase 2) + packed (val,idx) group records (2 b64 LDS reads in
// phase 1 instead of 4 b32). All-f32 state & arithmetic.
__global__ __launch_bounds__(NTH, 1) void banyan_main(
    float* __restrict__ x, const double* __restrict__ norms_in, const double* __restrict__ num_in,
    const float* __restrict__ Wl, const float* __restrict__ Wr, const float* __restrict__ Bb,
    float* __restrict__ out) {
  __shared__ float cosL[SS];
  __shared__ float rcpN[SS];       // 1 / max(norm, eps)
  __shared__ unsigned listL[SS];   // next lo16, prev hi16 (0xFFFF = -1)
  __shared__ int next2L[SS];       // next[next[s]] (-1 = none)
  __shared__ __align__(8) f2 gRec[NG];  // {max, bitcast(idx)} per group
  __shared__ float r3v[3][16];     // [sum][row-slot: w*4 + row]

  const int t = threadIdx.x;
  const int lane = t & 63;
  const int w = t >> 6;
  const int m16 = lane & 15;
  const float NEGINF = -__builtin_inff();

  for (int s = t; s < SS; s += NTH) {
    rcpN[s] = (float)(1.0 / fmax(norms_in[s], EPSD));
    const int nx = (s + 1 < SS) ? (s + 1) : -1;
    const int pv = s - 1;
    listL[s] = ((unsigned)nx & 0xFFFFu) | (((unsigned)pv & 0xFFFFu) << 16);
    next2L[s] = (s + 2 < SS) ? (s + 2) : -1;
  }
  __syncthreads();
  for (int s = t; s < SS; s += NTH) {
    cosL[s] = (s < SS - 1)
                  ? (float)((num_in[s] * (double)rcpN[s]) * (double)rcpN[s + 1])
                  : NEGINF;
  }
  __syncthreads();
  for (int m = 0; m < NG / NW; ++m) {
    const int g = w * (NG / NW) + m;
    float v = cosL[g * GS + lane];
    int ix = g * GS + lane;
#pragma unroll
    for (int off = 32; off > 0; off >>= 1) {
      const float ov = __shfl_down(v, off, 64);
      const int oi = __shfl_down(ix, off, 64);
      if (ov > v || (ov == v && oi < ix)) { v = ov; ix = oi; }
    }
    if (lane == 0) { f2 r; r.x = v; r.y = __int_as_float(ix); gRec[g] = r; }
  }
  __syncthreads();

  // Thread t owns elements {4t, 4t+1, 4t+2, 4t+3} (one 16B chunk).
  const int e0 = 4 * t;
  const f4 wl = *(const f4*)&Wl[e0];
  const f4 wr = *(const f4*)&Wr[e0];
  const f4 bv = *(const f4*)&Bb[e0];
  int head = 0;

  for (int step = 0; step < SS - 1; ++step) {
    // ---- phase 1: argmax over 32 packed group records ----
    const f2 rA = gRec[m16];
    const f2 rB = gRec[m16 + 16];
    float v = rA.x;
    int ix = __float_as_int(rA.y);
    foldmaxf(v, ix, rB.x, __float_as_int(rB.y));
    amax_dppf<DPP_XOR1>(v, ix);
    amax_dppf<DPP_XOR2>(v, ix);
    amax_dppf<DPP_HMIR>(v, ix);
    amax_dppf<DPP_MIR>(v, ix);
    const int i = __builtin_amdgcn_readfirstlane(ix);
    // issue i-row load immediately (don't wait for the list round-trip)
    const f4 xi = *(const f4*)&x[(size_t)i * EE + e0];
    const unsigned pki = listL[i];   // broadcast LDS reads
    const int nj_raw = next2L[i];
    const int j = __builtin_amdgcn_readfirstlane((int)(short)(pki & 0xFFFFu));
    const int p = __builtin_amdgcn_readfirstlane((int)(short)(pki >> 16));
    const int nj = __builtin_amdgcn_readfirstlane(nj_raw);
    if (p < 0) head = j;
    const int p2 = (p >= 0) ? p : i;
    const int n2 = (nj >= 0) ? nj : i;

    // ---- phase 2: remaining row loads; stable scan + tanh in the window ----
    const f4 xj = *(const f4*)&x[(size_t)j * EE + e0];
    const f4 xp = *(const f4*)&x[(size_t)p2 * EE + e0];
    const f4 xn = *(const f4*)&x[(size_t)n2 * EE + e0];
    const float rcpP = rcpN[p2];
    const float rcpNN = rcpN[n2];
    const int gi_ = i >> 6;
    const int gp_ = (p >= 0) ? (p >> 6) : gi_;
    const int gj_ = j >> 6;
    const int grp = (w == 0) ? gi_ : (w == 1) ? gp_ : gj_;
    const int base = grp * GS + m16;

    // stable-group scan (masked i/p/j) — runs while the row loads fly.
    // max-with-min-index is order-independent, so folding cosP/cosJ later
    // (phase 3) gives the exact same result as the all-at-once scan.
    float stv = NEGINF; int sti = 0;
    if (w < 3) {
      float cc0 = cosL[base];
      float cc1 = cosL[base + 16];
      float cc2 = cosL[base + 32];
      float cc3 = cosL[base + 48];
      const int pos0 = base, pos1 = base + 16, pos2 = base + 32, pos3 = base + 48;
      if (pos0 == i || pos0 == p || pos0 == j) cc0 = NEGINF;
      if (pos1 == i || pos1 == p || pos1 == j) cc1 = NEGINF;
      if (pos2 == i || pos2 == p || pos2 == j) cc2 = NEGINF;
      if (pos3 == i || pos3 == p || pos3 == j) cc3 = NEGINF;
      float cv = cc0; int gx = pos0;
      foldmaxf(cv, gx, cc1, pos1);
      foldmaxf(cv, gx, cc2, pos2);
      foldmaxf(cv, gx, cc3, pos3);
      amax_dppf<DPP_XOR1>(cv, gx);
      amax_dppf<DPP_XOR2>(cv, gx);
      amax_dppf<DPP_HMIR>(cv, gx);
      amax_dppf<DPP_MIR>(cv, gx);
      stv = cv; sti = gx;
    }

    const float q0 = tanh_f32(fmaf(xi.x, wl.x, fmaf(xj.x, wr.x, bv.x)));
    const float q1 = tanh_f32(fmaf(xi.y, wl.y, fmaf(xj.y, wr.y, bv.y)));
    const float q2 = tanh_f32(fmaf(xi.z, wl.z, fmaf(xj.z, wr.z, bv.z)));
    const float q3 = tanh_f32(fmaf(xi.w, wl.w, fmaf(xj.w, wr.w, bv.w)));
    f4 st; st.x = q0; st.y = q1; st.z = q2; st.w = q3;
    *(f4*)&x[(size_t)j * EE + e0] = st;

    float s0 = fmaf(q0, q0, fmaf(q1, q1, fmaf(q2, q2, q3 * q3)));
    float s1 = fmaf(xp.x, q0, fmaf(xp.y, q1, fmaf(xp.z, q2, xp.w * q3)));
    float s2 = fmaf(q0, xn.x, fmaf(q1, xn.y, fmaf(q2, xn.z, q3 * xn.w)));
    s1 = (p >= 0) ? s1 : 0.0f;
    s2 = (nj >= 0) ? s2 : 0.0f;
    // DPP-only row reduce (16-lane rows); write 16 row partials
    s0 = dpp_addf<DPP_XOR1>(s0); s1 = dpp_addf<DPP_XOR1>(s1); s2 = dpp_addf<DPP_XOR1>(s2);
    s0 = dpp_addf<DPP_XOR2>(s0); s1 = dpp_addf<DPP_XOR2>(s1); s2 = dpp_addf<DPP_XOR2>(s2);
    s0 = dpp_addf<DPP_HMIR>(s0); s1 = dpp_addf<DPP_HMIR>(s1); s2 = dpp_addf<DPP_HMIR>(s2);
    s0 = dpp_addf<DPP_MIR>(s0);  s1 = dpp_addf<DPP_MIR>(s1);  s2 = dpp_addf<DPP_MIR>(s2);
    if (m16 == 0) {                  // lanes 0,16,32,48: row partials
      const int slot = w * 4 + (lane >> 4);
      r3v[0][slot] = s0; r3v[1][slot] = s1; r3v[2][slot] = s2;
    }
    __syncthreads();  // B

    // ---- phase 3: fold 16 partials + cosines + O(1) repair + writes ----
    float t0 = r3v[0][m16];
    float t1 = r3v[1][m16];
    float t2 = r3v[2][m16];
    t0 = dpp_addf<DPP_XOR1>(t0); t1 = dpp_addf<DPP_XOR1>(t1); t2 = dpp_addf<DPP_XOR1>(t2);
    t0 = dpp_addf<DPP_XOR2>(t0); t1 = dpp_addf<DPP_XOR2>(t1); t2 = dpp_addf<DPP_XOR2>(t2);
    t0 = dpp_addf<DPP_HMIR>(t0); t1 = dpp_addf<DPP_HMIR>(t1); t2 = dpp_addf<DPP_HMIR>(t2);
    t0 = dpp_addf<DPP_MIR>(t0);  t1 = dpp_addf<DPP_MIR>(t1);  t2 = dpp_addf<DPP_MIR>(t2);
    const float invnn = (t0 > EPSF * EPSF) ? rsqrt1f(t0) : 1e8f;
    const float cosP = (p >= 0) ? (t1 * rcpP) * invnn : NEGINF;
    const float cosJnew = (nj >= 0) ? (t2 * rcpNN) * invnn : NEGINF;
    if (w < 3) {
      float cv = stv; int gx = sti;
      if (p >= 0 && gp_ == grp) foldmaxf(cv, gx, cosP, p);
      if (gj_ == grp) foldmaxf(cv, gx, cosJnew, j);
      if (lane == 0) {              // dup groups: same value written twice
        f2 r; r.x = cv; r.y = __int_as_float(gx);
        gRec[grp] = r;
      }
    } else if (lane == 0) {  // wave 3: scalar LDS state updates
      cosL[i] = NEGINF;
      cosL[j] = cosJnew;
      rcpN[j] = invnn;
      listL[j] = ((unsigned)nj & 0xFFFFu) | (((unsigned)p & 0xFFFFu) << 16);
      if (p >= 0) {
        cosL[p] = cosP;
        const unsigned lp = listL[p];
        listL[p] = (lp & 0xFFFF0000u) | ((unsigned)j & 0xFFFFu);
        next2L[p] = nj;
        const int pp = (int)(short)(lp >> 16);
        if (pp >= 0) next2L[pp] = j;
      }
    }
    __syncthreads();  // C
  }

  {
    const f4 h = *(const f4*)&x[(size_t)head * EE + e0];
    *(f4*)&out[e0] = h;
  }
}

extern "C" void kernel_launch(void* const* d_in, const int* in_sizes, int n_in,
                              void* d_out, int out_size, void* d_ws, size_t ws_size,
                              hipStream_t stream) {
  const int* seqs = (const int*)d_in[0];
  const float* emb = (const float*)d_in[1];
  const float* Wl = (const float*)d_in[2];
  const float* Wr = (const float*)d_in[3];
  const float* Bb = (const float*)d_in[4];
  float* out = (float*)d_out;

  const size_t xbytesF = (size_t)SS * EE * sizeof(float);
  float* x = (float*)d_ws;
  double* norms = (double*)((char*)d_ws + xbytesF);
  double* num = norms + SS;
  hipLaunchKernelGGL(banyan_init, dim3(SS), dim3(256), 0, stream, seqs, emb, x, norms);
  hipLaunchKernelGGL(banyan_dots, dim3(SS - 1), dim3(256), 0, stream, x, num);
  hipLaunchKernelGGL(banyan_main, dim3(1), dim3(NTH), 0, stream,
                     x, norms, num, Wl, Wr, Bb, out);
}

// Round 17
// 2571.618 us; speedup vs baseline: 1.1086x; 1.0036x over previous
//
#include <hip/hip_runtime.h>
#include <math.h>

#define SS 2048
#define EE 1024
#define EPSD 1e-8
#define EPSF 1e-8f
#define NTH 256          // 4 waves, 1 per SIMD
#define NW  4
#define NG  32           // cosine groups
#define GS  64           // group size

#define DPP_XOR1 0xB1    // quad_perm [1,0,3,2]
#define DPP_XOR2 0x4E    // quad_perm [2,3,0,1]
#define DPP_HMIR 0x141   // row_half_mirror
#define DPP_MIR  0x140   // row_mirror

using f4 = float __attribute__((ext_vector_type(4)));
using f2 = float __attribute__((ext_vector_type(2)));

// LDS-only barrier: __syncthreads() forces s_waitcnt vmcnt(0) (drains the
// in-flight parent store, ~200-400cy). x-traffic is within-thread-only
// (thread t touches columns 4t..4t+3 of every row), so global ordering is
// handled by the wave's own vmcnt logic; barriers only need LDS visibility.
__device__ __forceinline__ void bar_lds() {
  asm volatile("s_waitcnt lgkmcnt(0)" ::: "memory");
  __builtin_amdgcn_s_barrier();
  __builtin_amdgcn_sched_barrier(0);
}

// ---- f32 DPP primitives (single mov_dpp per stage) ----
template <int CTRL>
__device__ __forceinline__ float mov_dpp_f32(float v) {
  union { float f; int i; } a; a.f = v;
  const int n = __builtin_amdgcn_mov_dpp(a.i, CTRL, 0xF, 0xF, true);
  union { int i; float f; } r; r.i = n;
  return r.f;
}

template <int CTRL>
__device__ __forceinline__ float dpp_addf(float v) { return v + mov_dpp_f32<CTRL>(v); }

template <int CTRL>
__device__ __forceinline__ void amax_dppf(float& v, int& ix) {
  const float ov = mov_dpp_f32<CTRL>(v);
  const int oi = __builtin_amdgcn_mov_dpp(ix, CTRL, 0xF, 0xF, true);
  if (ov > v || (ov == v && oi < ix)) { v = ov; ix = oi; }
}

__device__ __forceinline__ void foldmaxf(float& v, int& ix, float ov, int oi) {
  if (ov > v || (ov == v && oi < ix)) { v = ov; ix = oi; }
}

// f32 1/sqrt: v_rsq_f32 + 1 Newton (~1 ulp).
__device__ __forceinline__ float rsqrt1f(float x) {
  float y = __builtin_amdgcn_rsqf(x);
  y = y * fmaf(-0.5f * x * y, y, 1.5f);
  return y;
}

// f32 1/x: v_rcp_f32 + 1 Newton (~1 ulp).
__device__ __forceinline__ float rcp1f(float x) {
  float y = __builtin_amdgcn_rcpf(x);
  y = y * fmaf(-x, y, 2.0f);
  return y;
}

// f32 tanh for |z| <= ~1.2, rel err ~2e-7: odd Taylor at z/2 (7 terms) + doubling.
__device__ __forceinline__ float tanh_f32(float z) {
  const float u = 0.5f * z;
  const float s = u * u;
  float P = fmaf(s, -929569.0f / 638512875.0f, 21844.0f / 6081075.0f);  // c15,c13
  P = fmaf(s, P, -1382.0f / 155925.0f);   // c11
  P = fmaf(s, P, 62.0f / 2835.0f);        // c9
  P = fmaf(s, P, -17.0f / 315.0f);        // c7
  P = fmaf(s, P, 2.0f / 15.0f);           // c5
  P = fmaf(s, P, -1.0f / 3.0f);           // c3
  const float t = fmaf(u * s, P, u);      // tanh(z/2)
  const float den = fmaf(t, t, 1.0f);
  return (2.0f * t) * rcp1f(den);
}

__device__ __forceinline__ double wave_sum64(double v) {
#pragma unroll
  for (int off = 32; off > 0; off >>= 1) v += __shfl_down(v, off, 64);
  return v;
}

__global__ void banyan_init(const int* __restrict__ seqs, const float* __restrict__ emb,
                            float* __restrict__ x, double* __restrict__ norms) {
  __shared__ double sh[4];
  const int s = blockIdx.x;
  const int row = seqs[s];
  double acc = 0.0;
  for (int e = threadIdx.x; e < EE; e += 256) {
    const float v = emb[(size_t)row * EE + e];
    x[(size_t)s * EE + e] = v;
    acc += (double)v * (double)v;
  }
  acc = wave_sum64(acc);
  const int lane = threadIdx.x & 63;
  const int w = threadIdx.x >> 6;
  if (lane == 0) sh[w] = acc;
  __syncthreads();
  if (threadIdx.x == 0) norms[s] = sqrt(sh[0] + sh[1] + sh[2] + sh[3]);
}

__global__ void banyan_dots(const float* __restrict__ x, double* __restrict__ num) {
  __shared__ double sh[4];
  const int s = blockIdx.x;
  double acc = 0.0;
  for (int e = threadIdx.x; e < EE; e += 256) {
    acc += (double)x[(size_t)s * EE + e] * (double)x[(size_t)(s + 1) * EE + e];
  }
  acc = wave_sum64(acc);
  const int lane = threadIdx.x & 63;
  const int w = threadIdx.x >> 6;
  if (lane == 0) sh[w] = acc;
  __syncthreads();
  if (threadIdx.x == 0) num[s] = sh[0] + sh[1] + sh[2] + sh[3];
}

// R16 skeleton (best: 2581us) with LDS-only raw barriers (no vmcnt drain)
// and the parent store moved after barrier B (issues under phase-3 compute).
__global__ __launch_bounds__(NTH, 1) void banyan_main(
    float* __restrict__ x, const double* __restrict__ norms_in, const double* __restrict__ num_in,
    const float* __restrict__ Wl, const float* __restrict__ Wr, const float* __restrict__ Bb,
    float* __restrict__ out) {
  __shared__ float cosL[SS];
  __shared__ float rcpN[SS];       // 1 / max(norm, eps)
  __shared__ unsigned listL[SS];   // next lo16, prev hi16 (0xFFFF = -1)
  __shared__ int next2L[SS];       // next[next[s]] (-1 = none)
  __shared__ __align__(8) f2 gRec[NG];  // {max, bitcast(idx)} per group
  __shared__ float r3v[3][16];     // [sum][row-slot: w*4 + row]

  const int t = threadIdx.x;
  const int lane = t & 63;
  const int w = t >> 6;
  const int m16 = lane & 15;
  const float NEGINF = -__builtin_inff();

  for (int s = t; s < SS; s += NTH) {
    rcpN[s] = (float)(1.0 / fmax(norms_in[s], EPSD));
    const int nx = (s + 1 < SS) ? (s + 1) : -1;
    const int pv = s - 1;
    listL[s] = ((unsigned)nx & 0xFFFFu) | (((unsigned)pv & 0xFFFFu) << 16);
    next2L[s] = (s + 2 < SS) ? (s + 2) : -1;
  }
  __syncthreads();
  for (int s = t; s < SS; s += NTH) {
    cosL[s] = (s < SS - 1)
                  ? (float)((num_in[s] * (double)rcpN[s]) * (double)rcpN[s + 1])
                  : NEGINF;
  }
  __syncthreads();
  for (int m = 0; m < NG / NW; ++m) {
    const int g = w * (NG / NW) + m;
    float v = cosL[g * GS + lane];
    int ix = g * GS + lane;
#pragma unroll
    for (int off = 32; off > 0; off >>= 1) {
      const float ov = __shfl_down(v, off, 64);
      const int oi = __shfl_down(ix, off, 64);
      if (ov > v || (ov == v && oi < ix)) { v = ov; ix = oi; }
    }
    if (lane == 0) { f2 r; r.x = v; r.y = __int_as_float(ix); gRec[g] = r; }
  }
  __syncthreads();

  // Thread t owns elements {4t, 4t+1, 4t+2, 4t+3} (one 16B chunk).
  const int e0 = 4 * t;
  const f4 wl = *(const f4*)&Wl[e0];
  const f4 wr = *(const f4*)&Wr[e0];
  const f4 bv = *(const f4*)&Bb[e0];
  int head = 0;

  for (int step = 0; step < SS - 1; ++step) {
    // ---- phase 1: argmax over 32 packed group records ----
    const f2 rA = gRec[m16];
    const f2 rB = gRec[m16 + 16];
    float v = rA.x;
    int ix = __float_as_int(rA.y);
    foldmaxf(v, ix, rB.x, __float_as_int(rB.y));
    amax_dppf<DPP_XOR1>(v, ix);
    amax_dppf<DPP_XOR2>(v, ix);
    amax_dppf<DPP_HMIR>(v, ix);
    amax_dppf<DPP_MIR>(v, ix);
    const int i = __builtin_amdgcn_readfirstlane(ix);
    // issue i-row load immediately (don't wait for the list round-trip)
    const f4 xi = *(const f4*)&x[(size_t)i * EE + e0];
    const unsigned pki = listL[i];   // broadcast LDS reads
    const int nj_raw = next2L[i];
    const int j = __builtin_amdgcn_readfirstlane((int)(short)(pki & 0xFFFFu));
    const int p = __builtin_amdgcn_readfirstlane((int)(short)(pki >> 16));
    const int nj = __builtin_amdgcn_readfirstlane(nj_raw);
    if (p < 0) head = j;
    const int p2 = (p >= 0) ? p : i;
    const int n2 = (nj >= 0) ? nj : i;

    // ---- phase 2: remaining row loads; stable scan + tanh in the window ----
    const f4 xj = *(const f4*)&x[(size_t)j * EE + e0];
    const f4 xp = *(const f4*)&x[(size_t)p2 * EE + e0];
    const f4 xn = *(const f4*)&x[(size_t)n2 * EE + e0];
    const float rcpP = rcpN[p2];
    const float rcpNN = rcpN[n2];
    const int gi_ = i >> 6;
    const int gp_ = (p >= 0) ? (p >> 6) : gi_;
    const int gj_ = j >> 6;
    const int grp = (w == 0) ? gi_ : (w == 1) ? gp_ : gj_;
    const int base = grp * GS + m16;

    // stable-group scan (masked i/p/j) — runs while the row loads fly.
    float stv = NEGINF; int sti = 0;
    if (w < 3) {
      float cc0 = cosL[base];
      float cc1 = cosL[base + 16];
      float cc2 = cosL[base + 32];
      float cc3 = cosL[base + 48];
      const int pos0 = base, pos1 = base + 16, pos2 = base + 32, pos3 = base + 48;
      if (pos0 == i || pos0 == p || pos0 == j) cc0 = NEGINF;
      if (pos1 == i || pos1 == p || pos1 == j) cc1 = NEGINF;
      if (pos2 == i || pos2 == p || pos2 == j) cc2 = NEGINF;
      if (pos3 == i || pos3 == p || pos3 == j) cc3 = NEGINF;
      float cv = cc0; int gx = pos0;
      foldmaxf(cv, gx, cc1, pos1);
      foldmaxf(cv, gx, cc2, pos2);
      foldmaxf(cv, gx, cc3, pos3);
      amax_dppf<DPP_XOR1>(cv, gx);
      amax_dppf<DPP_XOR2>(cv, gx);
      amax_dppf<DPP_HMIR>(cv, gx);
      amax_dppf<DPP_MIR>(cv, gx);
      stv = cv; sti = gx;
    }

    const float q0 = tanh_f32(fmaf(xi.x, wl.x, fmaf(xj.x, wr.x, bv.x)));
    const float q1 = tanh_f32(fmaf(xi.y, wl.y, fmaf(xj.y, wr.y, bv.y)));
    const float q2 = tanh_f32(fmaf(xi.z, wl.z, fmaf(xj.z, wr.z, bv.z)));
    const float q3 = tanh_f32(fmaf(xi.w, wl.w, fmaf(xj.w, wr.w, bv.w)));

    float s0 = fmaf(q0, q0, fmaf(q1, q1, fmaf(q2, q2, q3 * q3)));
    float s1 = fmaf(xp.x, q0, fmaf(xp.y, q1, fmaf(xp.z, q2, xp.w * q3)));
    float s2 = fmaf(q0, xn.x, fmaf(q1, xn.y, fmaf(q2, xn.z, q3 * xn.w)));
    s1 = (p >= 0) ? s1 : 0.0f;
    s2 = (nj >= 0) ? s2 : 0.0f;
    // DPP-only row reduce (16-lane rows); write 16 row partials
    s0 = dpp_addf<DPP_XOR1>(s0); s1 = dpp_addf<DPP_XOR1>(s1); s2 = dpp_addf<DPP_XOR1>(s2);
    s0 = dpp_addf<DPP_XOR2>(s0); s1 = dpp_addf<DPP_XOR2>(s1); s2 = dpp_addf<DPP_XOR2>(s2);
    s0 = dpp_addf<DPP_HMIR>(s0); s1 = dpp_addf<DPP_HMIR>(s1); s2 = dpp_addf<DPP_HMIR>(s2);
    s0 = dpp_addf<DPP_MIR>(s0);  s1 = dpp_addf<DPP_MIR>(s1);  s2 = dpp_addf<DPP_MIR>(s2);
    if (m16 == 0) {                  // lanes 0,16,32,48: row partials
      const int slot = w * 4 + (lane >> 4);
      r3v[0][slot] = s0; r3v[1][slot] = s1; r3v[2][slot] = s2;
    }
    bar_lds();  // B — LDS-only barrier, no vmcnt drain

    // ---- phase 3: parent store (issues under compute), fold, repair ----
    {
      f4 st; st.x = q0; st.y = q1; st.z = q2; st.w = q3;
      *(f4*)&x[(size_t)j * EE + e0] = st;
    }
    float t0 = r3v[0][m16];
    float t1 = r3v[1][m16];
    float t2 = r3v[2][m16];
    t0 = dpp_addf<DPP_XOR1>(t0); t1 = dpp_addf<DPP_XOR1>(t1); t2 = dpp_addf<DPP_XOR1>(t2);
    t0 = dpp_addf<DPP_XOR2>(t0); t1 = dpp_addf<DPP_XOR2>(t1); t2 = dpp_addf<DPP_XOR2>(t2);
    t0 = dpp_addf<DPP_HMIR>(t0); t1 = dpp_addf<DPP_HMIR>(t1); t2 = dpp_addf<DPP_HMIR>(t2);
    t0 = dpp_addf<DPP_MIR>(t0);  t1 = dpp_addf<DPP_MIR>(t1);  t2 = dpp_addf<DPP_MIR>(t2);
    const float invnn = (t0 > EPSF * EPSF) ? rsqrt1f(t0) : 1e8f;
    const float cosP = (p >= 0) ? (t1 * rcpP) * invnn : NEGINF;
    const float cosJnew = (nj >= 0) ? (t2 * rcpNN) * invnn : NEGINF;
    if (w < 3) {
      float cv = stv; int gx = sti;
      if (p >= 0 && gp_ == grp) foldmaxf(cv, gx, cosP, p);
      if (gj_ == grp) foldmaxf(cv, gx, cosJnew, j);
      if (lane == 0) {              // dup groups: same value written twice
        f2 r; r.x = cv; r.y = __int_as_float(gx);
        gRec[grp] = r;
      }
    } else if (lane == 0) {  // wave 3: scalar LDS state updates
      cosL[i] = NEGINF;
      cosL[j] = cosJnew;
      rcpN[j] = invnn;
      listL[j] = ((unsigned)nj & 0xFFFFu) | (((unsigned)p & 0xFFFFu) << 16);
      if (p >= 0) {
        cosL[p] = cosP;
        const unsigned lp = listL[p];
        listL[p] = (lp & 0xFFFF0000u) | ((unsigned)j & 0xFFFFu);
        next2L[p] = nj;
        const int pp = (int)(short)(lp >> 16);
        if (pp >= 0) next2L[pp] = j;
      }
    }
    bar_lds();  // C — LDS-only barrier
  }

  {
    const f4 h = *(const f4*)&x[(size_t)head * EE + e0];
    *(f4*)&out[e0] = h;
  }
}

extern "C" void kernel_launch(void* const* d_in, const int* in_sizes, int n_in,
                              void* d_out, int out_size, void* d_ws, size_t ws_size,
                              hipStream_t stream) {
  const int* seqs = (const int*)d_in[0];
  const float* emb = (const float*)d_in[1];
  const float* Wl = (const float*)d_in[2];
  const float* Wr = (const float*)d_in[3];
  const float* Bb = (const float*)d_in[4];
  float* out = (float*)d_out;

  const size_t xbytesF = (size_t)SS * EE * sizeof(float);
  float* x = (float*)d_ws;
  double* norms = (double*)((char*)d_ws + xbytesF);
  double* num = norms + SS;
  hipLaunchKernelGGL(banyan_init, dim3(SS), dim3(256), 0, stream, seqs, emb, x, norms);
  hipLaunchKernelGGL(banyan_dots, dim3(SS - 1), dim3(256), 0, stream, x, num);
  hipLaunchKernelGGL(banyan_main, dim3(1), dim3(NTH), 0, stream,
                     x, norms, num, Wl, Wr, Bb, out);
}